// Round 4
// baseline (1004.869 us; speedup 1.0000x reference)
//
#include <hip/hip_runtime.h>
#include <hip/hip_bf16.h>

// Problem constants
#define NN    8192
#define FEAT  64
#define HIDD  128
#define EMBD  128

typedef __bf16 bf16x8 __attribute__((ext_vector_type(8)));
typedef float  f32x4  __attribute__((ext_vector_type(4)));

__device__ __forceinline__ void gload16(const void* g, void* l) {
    __builtin_amdgcn_global_load_lds(
        (const __attribute__((address_space(1))) void*)g,
        (__attribute__((address_space(3))) void*)l, 16, 0, 0);
}

// ---------------------------------------------------------------------------
// proj_pack: V_r = X @ W_r^T, stored as bf16 in MFMA B-fragment layout:
//   Vp[r][kb][n][lane][j]: element = V_r[kb*32 + (lane>>4)*8 + j][n*16 + (lane&15)]
// ---------------------------------------------------------------------------
template<int KIN>
__global__ __launch_bounds__(256) void proj_pack(
    const float* __restrict__ X, const float* __restrict__ W0,
    const float* __restrict__ W1, const float* __restrict__ W2,
    __bf16* __restrict__ Vp)
{
    size_t e = (size_t)blockIdx.x * 256 + threadIdx.x;   // < 3 * 2^20
    int j  = (int)(e & 7);
    int l  = (int)((e >> 3) & 63);
    int n  = (int)((e >> 9) & 7);
    int kb = (int)((e >> 12) & 255);
    int r  = (int)(e >> 20);
    int krow = kb * 32 + (l >> 4) * 8 + j;
    int col  = n * 16 + (l & 15);
    const float* w = (r == 0 ? W0 : (r == 1 ? W1 : W2)) + (size_t)col * KIN;
    const float* x = X + (size_t)krow * KIN;
    float s = 0.f;
#pragma unroll
    for (int t = 0; t < KIN; t += 4) {
        f32x4 xv = *(const f32x4*)(x + t);
        f32x4 wv = *(const f32x4*)(w + t);
        s += xv[0]*wv[0] + xv[1]*wv[1] + xv[2]*wv[2] + xv[3]*wv[3];
    }
    Vp[e] = (__bf16)s;
}

// ---------------------------------------------------------------------------
// gemm_AV v4: single-wave blocks, barrier-free counted-vmcnt pipeline.
// Block: 64 thr (1 wave); tile 64 rows x 128 cols; acc[4][8] (128 AGPR).
// Per K-step (BK=32): 16 async gload16 (8 A fragment-packed via per-lane
// source addressing, 8 B already packed) into one of 3 LDS bufs (16KB each).
// Loop: issue stage(t+2) -> s_waitcnt vmcnt(32) (two stages in flight) ->
// 16 lane-contiguous ds_read_b128 -> cvt -> 32 MFMA. No __syncthreads.
// Grid (128 mt, 8 ch) = 1024 blocks; LDS 48KB -> 3 blocks/CU.
// ---------------------------------------------------------------------------
__global__ __launch_bounds__(64) void gemm_AV(
    const float* __restrict__ A0, const float* __restrict__ A1,
    const float* __restrict__ A2,
    const __bf16* __restrict__ Vp, float* __restrict__ P)
{
    __shared__ __align__(16) unsigned char sbuf[3][16384];

    const int mt = blockIdx.x;            // 0..127 (64-row tile)
    const int ch = blockIdx.y;            // 0..7   (1024-K chunk)
    const int l  = threadIdx.x;           // 0..63
    const int l15 = l & 15, l4 = l >> 4;
    const int rowblk = mt * 64;

    f32x4 acc[4][8];
#pragma unroll
    for (int m = 0; m < 4; m++)
#pragma unroll
        for (int n = 0; n < 8; n++) acc[m][n] = (f32x4){0.f, 0.f, 0.f, 0.f};

    // per-lane A source offset (floats): row l15 within 16-row group, k l4*8
    const size_t aoff = (size_t)l15 * NN + (size_t)l4 * 8;

    auto stage = [&](int t) {
        const int r = t >> 5;                       // 0..2
        const float* Ar = (r == 0) ? A0 : (r == 1) ? A1 : A2;
        const int kglob = ch * 1024 + (t & 31) * 32;
        unsigned char* dst = sbuf[t % 3];
        // A: 8 insts; inst (m,h): lane l fetches A[rowblk+m*16+l15][kglob+l4*8+h*4 ..+4]
        // -> LDS (m*2+h)*1KB + lane*16 (fragment-packed, lane-contiguous)
        const float* abase = Ar + (size_t)rowblk * NN + kglob + aoff;
#pragma unroll
        for (int m = 0; m < 4; ++m) {
            gload16(abase + (size_t)m * 16 * NN,     dst + (m * 2 + 0) * 1024);
            gload16(abase + (size_t)m * 16 * NN + 4, dst + (m * 2 + 1) * 1024);
        }
        // B: 8 insts; frag n -> LDS 8192 + n*1KB + lane*16 (Vp already packed)
        const __bf16* bbase = Vp + ((size_t)r << 20) + (size_t)(kglob >> 5) * 4096 + l * 8;
#pragma unroll
        for (int q = 0; q < 8; ++q)
            gload16(bbase + q * 512, dst + 8192 + q * 1024);
    };

    stage(0);
    stage(1);

    for (int t = 0; t < 96; ++t) {
        if (t < 94) stage(t + 2);
        if (t < 94)      asm volatile("s_waitcnt vmcnt(32)" ::: "memory");
        else if (t == 94) asm volatile("s_waitcnt vmcnt(16)" ::: "memory");
        else              asm volatile("s_waitcnt vmcnt(0)"  ::: "memory");

        const unsigned char* buf = sbuf[t % 3];
        bf16x8 bfr[8];
#pragma unroll
        for (int n = 0; n < 8; ++n)
            bfr[n] = *(const bf16x8*)(buf + 8192 + n * 1024 + l * 16);
#pragma unroll
        for (int m = 0; m < 4; ++m) {
            f32x4 lo = *(const f32x4*)(buf + (m * 2 + 0) * 1024 + l * 16);
            f32x4 hi = *(const f32x4*)(buf + (m * 2 + 1) * 1024 + l * 16);
            bf16x8 af;
            af[0] = (__bf16)lo[0]; af[1] = (__bf16)lo[1];
            af[2] = (__bf16)lo[2]; af[3] = (__bf16)lo[3];
            af[4] = (__bf16)hi[0]; af[5] = (__bf16)hi[1];
            af[6] = (__bf16)hi[2]; af[7] = (__bf16)hi[3];
#pragma unroll
            for (int n = 0; n < 8; ++n)
                acc[m][n] = __builtin_amdgcn_mfma_f32_16x16x32_bf16(af, bfr[n], acc[m][n], 0, 0, 0);
        }
    }

    // C/D layout: col = lane&15, row = (lane>>4)*4 + i
    float* Pp = P + (size_t)ch * NN * 128;
#pragma unroll
    for (int m = 0; m < 4; m++)
#pragma unroll
        for (int n = 0; n < 8; n++) {
            int col = n * 16 + l15;
#pragma unroll
            for (int i = 0; i < 4; i++) {
                int row = rowblk + m * 16 + l4 * 4 + i;
                Pp[(size_t)row * 128 + col] = acc[m][n][i];
            }
        }
}

// ---------------------------------------------------------------------------
// reduce kernels: sum 8 partial slabs + bias (+relu), f32x4 vectorized
// ---------------------------------------------------------------------------
__global__ __launch_bounds__(256) void reduce_relu(
    const float* __restrict__ P, const float* __restrict__ bias,
    float* __restrict__ Hout)
{
    size_t g = (size_t)blockIdx.x * 256 + threadIdx.x;   // < 2^18
    size_t idx4 = g * 4;
    f32x4 s = *(const f32x4*)(bias + (idx4 & 127));
#pragma unroll
    for (int p = 0; p < 8; p++) s += *(const f32x4*)(P + (size_t)p * (NN * 128) + idx4);
#pragma unroll
    for (int c = 0; c < 4; c++) s[c] = s[c] > 0.f ? s[c] : 0.f;
    *(f32x4*)(Hout + idx4) = s;
}

__global__ __launch_bounds__(256) void reduce_z(
    const float* __restrict__ P, const float* __restrict__ bias,
    float* __restrict__ Zout, __bf16* __restrict__ Zb)
{
    size_t g = (size_t)blockIdx.x * 256 + threadIdx.x;
    size_t idx4 = g * 4;
    f32x4 s = *(const f32x4*)(bias + (idx4 & 127));
#pragma unroll
    for (int p = 0; p < 8; p++) s += *(const f32x4*)(P + (size_t)p * (NN * 128) + idx4);
    *(f32x4*)(Zout + idx4) = s;
#pragma unroll
    for (int c = 0; c < 4; c++) Zb[idx4 + c] = (__bf16)s[c];
}

// ---------------------------------------------------------------------------
// zzt: A_hat = Z @ Z^T, K=128, from row-major bf16 Z (2 MB, cache-resident)
// ---------------------------------------------------------------------------
__global__ __launch_bounds__(256) void zzt(
    const __bf16* __restrict__ Zb, float* __restrict__ Out)
{
    const int bx = blockIdx.x;   // col tile
    const int by = blockIdx.y;   // row tile
    const int tid = threadIdx.x;
    const int w = tid >> 6, l = tid & 63;
    const int l15 = l & 15, l4 = l >> 4;
    const int rowbase = by * 128 + w * 32;
    const int colbase = bx * 128;

    f32x4 acc[2][8];
#pragma unroll
    for (int m = 0; m < 2; m++)
#pragma unroll
        for (int n = 0; n < 8; n++) acc[m][n] = (f32x4){0.f, 0.f, 0.f, 0.f};

#pragma unroll
    for (int ks = 0; ks < 128; ks += 32) {
        bf16x8 af[2];
#pragma unroll
        for (int m = 0; m < 2; m++)
            af[m] = *(const bf16x8*)(Zb + (size_t)(rowbase + m * 16 + l15) * 128 + ks + l4 * 8);
#pragma unroll
        for (int n = 0; n < 8; n++) {
            bf16x8 bfr = *(const bf16x8*)(Zb + (size_t)(colbase + n * 16 + l15) * 128 + ks + l4 * 8);
            acc[0][n] = __builtin_amdgcn_mfma_f32_16x16x32_bf16(af[0], bfr, acc[0][n], 0, 0, 0);
            acc[1][n] = __builtin_amdgcn_mfma_f32_16x16x32_bf16(af[1], bfr, acc[1][n], 0, 0, 0);
        }
    }

#pragma unroll
    for (int m = 0; m < 2; m++)
#pragma unroll
        for (int n = 0; n < 8; n++) {
            int col = colbase + n * 16 + l15;
#pragma unroll
            for (int i = 0; i < 4; i++) {
                int row = rowbase + m * 16 + l4 * 4 + i;
                Out[(size_t)row * NN + col] = acc[m][n][i];
            }
        }
}

// ---------------------------------------------------------------------------
extern "C" void kernel_launch(void* const* d_in, const int* in_sizes, int n_in,
                              void* d_out, int out_size, void* d_ws, size_t ws_size,
                              hipStream_t stream)
{
    // setup_inputs() order: H, A_buys, A_views, A_rates,
    //   W1_0, W2_0, W1_1, W2_1, W1_2, W2_2, b1, b2
    const float* H    = (const float*)d_in[0];
    const float* A0   = (const float*)d_in[1];
    const float* A1   = (const float*)d_in[2];
    const float* A2   = (const float*)d_in[3];
    const float* W1_0 = (const float*)d_in[4];
    const float* W2_0 = (const float*)d_in[5];
    const float* W1_1 = (const float*)d_in[6];
    const float* W2_1 = (const float*)d_in[7];
    const float* W1_2 = (const float*)d_in[8];
    const float* W2_2 = (const float*)d_in[9];
    const float* b1   = (const float*)d_in[10];
    const float* b2   = (const float*)d_in[11];

    float* Zout = (float*)d_out;                     // [8192][128]
    float* Ahat = (float*)d_out + (size_t)NN * EMBD; // [8192][8192]

    char* ws = (char*)d_ws;
    __bf16* Vp = (__bf16*)ws;                        //  6 MB packed V (3 x 2MB)
    float*  P  = (float*)(ws + ((size_t)8  << 20));  // 32 MB partials (8 slabs)
    float*  H1 = (float*)(ws + ((size_t)40 << 20));  //  4 MB
    __bf16* Zb = (__bf16*)(ws + ((size_t)44 << 20)); //  2 MB

    // Layer 1
    proj_pack<FEAT><<<12288, 256, 0, stream>>>(H, W1_0, W1_1, W1_2, Vp);
    gemm_AV<<<dim3(128, 8), 64, 0, stream>>>(A0, A1, A2, Vp, P);
    reduce_relu<<<1024, 256, 0, stream>>>(P, b1, H1);

    // Layer 2
    proj_pack<HIDD><<<12288, 256, 0, stream>>>(H1, W2_0, W2_1, W2_2, Vp);
    gemm_AV<<<dim3(128, 8), 64, 0, stream>>>(A0, A1, A2, Vp, P);
    reduce_z<<<1024, 256, 0, stream>>>(P, b2, Zout, Zb);

    // Decoder
    zzt<<<dim3(64, 64), 256, 0, stream>>>(Zb, Ahat);
}

// Round 5
// 922.588 us; speedup vs baseline: 1.0892x; 1.0892x over previous
//
#include <hip/hip_runtime.h>
#include <hip/hip_bf16.h>

// Problem constants
#define NN    8192
#define FEAT  64
#define HIDD  128
#define EMBD  128

typedef __bf16 bf16x8 __attribute__((ext_vector_type(8)));
typedef float  f32x4  __attribute__((ext_vector_type(4)));

__device__ __forceinline__ void gload16(const void* g, void* l) {
    __builtin_amdgcn_global_load_lds(
        (const __attribute__((address_space(1))) void*)g,
        (__attribute__((address_space(3))) void*)l, 16, 0, 0);
}

// ---------------------------------------------------------------------------
// proj_pack: V_r = X @ W_r^T, stored as bf16 in MFMA B-fragment layout:
//   Vp[r][kb][n][lane][j]: element = V_r[kb*32 + (lane>>4)*8 + j][n*16 + (lane&15)]
// ---------------------------------------------------------------------------
template<int KIN>
__global__ __launch_bounds__(256) void proj_pack(
    const float* __restrict__ X, const float* __restrict__ W0,
    const float* __restrict__ W1, const float* __restrict__ W2,
    __bf16* __restrict__ Vp)
{
    size_t e = (size_t)blockIdx.x * 256 + threadIdx.x;   // < 3 * 2^20
    int j  = (int)(e & 7);
    int l  = (int)((e >> 3) & 63);
    int n  = (int)((e >> 9) & 7);
    int kb = (int)((e >> 12) & 255);
    int r  = (int)(e >> 20);
    int krow = kb * 32 + (l >> 4) * 8 + j;
    int col  = n * 16 + (l & 15);
    const float* w = (r == 0 ? W0 : (r == 1 ? W1 : W2)) + (size_t)col * KIN;
    const float* x = X + (size_t)krow * KIN;
    float s = 0.f;
#pragma unroll
    for (int t = 0; t < KIN; t += 4) {
        f32x4 xv = *(const f32x4*)(x + t);
        f32x4 wv = *(const f32x4*)(w + t);
        s += xv[0]*wv[0] + xv[1]*wv[1] + xv[2]*wv[2] + xv[3]*wv[3];
    }
    Vp[e] = (__bf16)s;
}

// ---------------------------------------------------------------------------
// gemm_AV v5: m97-style. Block 256 thr (4 waves); tile BM=64 x BN=128, BK=32.
// ALL global traffic via global_load_lds (nothing register-consumed -> vmcnt
// stays decoupled). 2 LDS buffers, one __syncthreads per step placed BEFORE
// next stage-issue: barrier drains stage(t), stage(t+1) flies over compute.
// A staged with within-row XOR 16B-block swizzle (global src stays contiguous
// per row; LDS reads spread evenly over banks). Grid (128 mt, 8 ch) = 1024
// blocks; LDS 32KB -> 4 resident blocks/CU = 16 waves/CU for overlap.
// ---------------------------------------------------------------------------
__global__ __launch_bounds__(256) void gemm_AV(
    const float* __restrict__ A0, const float* __restrict__ A1,
    const float* __restrict__ A2,
    const __bf16* __restrict__ Vp, float* __restrict__ P)
{
    // per buffer: A = 64 rows x 32 f32 (8KB, block-swizzled), B = 8KB packed
    __shared__ __align__(16) unsigned char sbuf[2][16384];

    const int mt = blockIdx.x;            // 0..127 (64-row tile)
    const int ch = blockIdx.y;            // 0..7   (1024-K chunk)
    const int tid = threadIdx.x;
    const int w = tid >> 6, l = tid & 63;
    const int l15 = l & 15, l4 = l >> 4;
    const int wr = w >> 1, wc = w & 1;    // wave quadrant: rows wr*32, cols wc*64
    const int rowblk = mt * 64;

    f32x4 acc[2][4];
#pragma unroll
    for (int m = 0; m < 2; m++)
#pragma unroll
        for (int n = 0; n < 4; n++) acc[m][n] = (f32x4){0.f, 0.f, 0.f, 0.f};

    // A staging constants: this wave handles insts j = 2w, 2w+1.
    // Inst j, lane l -> slot s = j*64+l; LDS row = s>>3, permuted blk = s&7;
    // global blk = (s&7) ^ (row&7). Source row-contiguous (8 lanes x 16B).
    auto stage = [&](int t, int buf) {
        const int r = t >> 5;                       // 0..2
        const float* Ar = (r == 0) ? A0 : (r == 1) ? A1 : A2;
        const int kglob = ch * 1024 + (t & 31) * 32;
        unsigned char* dst = sbuf[buf];
#pragma unroll
        for (int q = 0; q < 2; ++q) {
            const int s    = (w * 2 + q) * 64 + l;
            const int row  = s >> 3;
            const int gblk = (s & 7) ^ (row & 7);
            gload16(Ar + (size_t)(rowblk + row) * NN + kglob + gblk * 4,
                    dst + s * 16);
        }
        // B: frags n = 2w, 2w+1 (Vp already fragment-packed, linear)
        const __bf16* bbase = Vp + ((size_t)r << 20) + (size_t)(kglob >> 5) * 4096;
#pragma unroll
        for (int q = 0; q < 2; ++q) {
            const int n = w * 2 + q;
            gload16(bbase + n * 512 + l * 8, dst + 8192 + n * 1024 + l * 16);
        }
    };

    stage(0, 0);

    for (int t = 0; t < 96; ++t) {
        __syncthreads();                  // drains vmcnt: stage(t) landed; all
                                          // waves done reading buf (t+1)&1
        if (t < 95) stage(t + 1, (t + 1) & 1);

        const unsigned char* buf = sbuf[t & 1];
        bf16x8 bfr[4];
#pragma unroll
        for (int n = 0; n < 4; ++n)
            bfr[n] = *(const bf16x8*)(buf + 8192 + (wc * 4 + n) * 1024 + l * 16);
#pragma unroll
        for (int m = 0; m < 2; ++m) {
            const int row = wr * 32 + m * 16 + l15;
            const int b0 = (2 * l4)     ^ (l15 & 7);
            const int b1 = (2 * l4 + 1) ^ (l15 & 7);
            f32x4 lo = *(const f32x4*)(buf + row * 128 + b0 * 16);
            f32x4 hi = *(const f32x4*)(buf + row * 128 + b1 * 16);
            bf16x8 af;
            af[0] = (__bf16)lo[0]; af[1] = (__bf16)lo[1];
            af[2] = (__bf16)lo[2]; af[3] = (__bf16)lo[3];
            af[4] = (__bf16)hi[0]; af[5] = (__bf16)hi[1];
            af[6] = (__bf16)hi[2]; af[7] = (__bf16)hi[3];
#pragma unroll
            for (int n = 0; n < 4; ++n)
                acc[m][n] = __builtin_amdgcn_mfma_f32_16x16x32_bf16(af, bfr[n], acc[m][n], 0, 0, 0);
        }
    }

    // C/D layout: col = lane&15, row = (lane>>4)*4 + i
    float* Pp = P + (size_t)ch * NN * 128;
#pragma unroll
    for (int m = 0; m < 2; m++)
#pragma unroll
        for (int n = 0; n < 4; n++) {
            int col = wc * 64 + n * 16 + l15;
#pragma unroll
            for (int i = 0; i < 4; i++) {
                int row = rowblk + wr * 32 + m * 16 + l4 * 4 + i;
                Pp[(size_t)row * 128 + col] = acc[m][n][i];
            }
        }
}

// ---------------------------------------------------------------------------
// reduce kernels: sum 8 partial slabs + bias (+relu), f32x4 vectorized
// ---------------------------------------------------------------------------
__global__ __launch_bounds__(256) void reduce_relu(
    const float* __restrict__ P, const float* __restrict__ bias,
    float* __restrict__ Hout)
{
    size_t g = (size_t)blockIdx.x * 256 + threadIdx.x;   // < 2^18
    size_t idx4 = g * 4;
    f32x4 s = *(const f32x4*)(bias + (idx4 & 127));
#pragma unroll
    for (int p = 0; p < 8; p++) s += *(const f32x4*)(P + (size_t)p * (NN * 128) + idx4);
#pragma unroll
    for (int c = 0; c < 4; c++) s[c] = s[c] > 0.f ? s[c] : 0.f;
    *(f32x4*)(Hout + idx4) = s;
}

__global__ __launch_bounds__(256) void reduce_z(
    const float* __restrict__ P, const float* __restrict__ bias,
    float* __restrict__ Zout, __bf16* __restrict__ Zb)
{
    size_t g = (size_t)blockIdx.x * 256 + threadIdx.x;
    size_t idx4 = g * 4;
    f32x4 s = *(const f32x4*)(bias + (idx4 & 127));
#pragma unroll
    for (int p = 0; p < 8; p++) s += *(const f32x4*)(P + (size_t)p * (NN * 128) + idx4);
    *(f32x4*)(Zout + idx4) = s;
#pragma unroll
    for (int c = 0; c < 4; c++) Zb[idx4 + c] = (__bf16)s[c];
}

// ---------------------------------------------------------------------------
// zzt: A_hat = Z @ Z^T, K=128, from row-major bf16 Z (2 MB, cache-resident)
// ---------------------------------------------------------------------------
__global__ __launch_bounds__(256) void zzt(
    const __bf16* __restrict__ Zb, float* __restrict__ Out)
{
    const int bx = blockIdx.x;   // col tile
    const int by = blockIdx.y;   // row tile
    const int tid = threadIdx.x;
    const int w = tid >> 6, l = tid & 63;
    const int l15 = l & 15, l4 = l >> 4;
    const int rowbase = by * 128 + w * 32;
    const int colbase = bx * 128;

    f32x4 acc[2][8];
#pragma unroll
    for (int m = 0; m < 2; m++)
#pragma unroll
        for (int n = 0; n < 8; n++) acc[m][n] = (f32x4){0.f, 0.f, 0.f, 0.f};

#pragma unroll
    for (int ks = 0; ks < 128; ks += 32) {
        bf16x8 af[2];
#pragma unroll
        for (int m = 0; m < 2; m++)
            af[m] = *(const bf16x8*)(Zb + (size_t)(rowbase + m * 16 + l15) * 128 + ks + l4 * 8);
#pragma unroll
        for (int n = 0; n < 8; n++) {
            bf16x8 bfr = *(const bf16x8*)(Zb + (size_t)(colbase + n * 16 + l15) * 128 + ks + l4 * 8);
            acc[0][n] = __builtin_amdgcn_mfma_f32_16x16x32_bf16(af[0], bfr, acc[0][n], 0, 0, 0);
            acc[1][n] = __builtin_amdgcn_mfma_f32_16x16x32_bf16(af[1], bfr, acc[1][n], 0, 0, 0);
        }
    }

#pragma unroll
    for (int m = 0; m < 2; m++)
#pragma unroll
        for (int n = 0; n < 8; n++) {
            int col = colbase + n * 16 + l15;
#pragma unroll
            for (int i = 0; i < 4; i++) {
                int row = rowbase + m * 16 + l4 * 4 + i;
                Out[(size_t)row * NN + col] = acc[m][n][i];
            }
        }
}

// ---------------------------------------------------------------------------
extern "C" void kernel_launch(void* const* d_in, const int* in_sizes, int n_in,
                              void* d_out, int out_size, void* d_ws, size_t ws_size,
                              hipStream_t stream)
{
    // setup_inputs() order: H, A_buys, A_views, A_rates,
    //   W1_0, W2_0, W1_1, W2_1, W1_2, W2_2, b1, b2
    const float* H    = (const float*)d_in[0];
    const float* A0   = (const float*)d_in[1];
    const float* A1   = (const float*)d_in[2];
    const float* A2   = (const float*)d_in[3];
    const float* W1_0 = (const float*)d_in[4];
    const float* W2_0 = (const float*)d_in[5];
    const float* W1_1 = (const float*)d_in[6];
    const float* W2_1 = (const float*)d_in[7];
    const float* W1_2 = (const float*)d_in[8];
    const float* W2_2 = (const float*)d_in[9];
    const float* b1   = (const float*)d_in[10];
    const float* b2   = (const float*)d_in[11];

    float* Zout = (float*)d_out;                     // [8192][128]
    float* Ahat = (float*)d_out + (size_t)NN * EMBD; // [8192][8192]

    char* ws = (char*)d_ws;
    __bf16* Vp = (__bf16*)ws;                        //  6 MB packed V (3 x 2MB)
    float*  P  = (float*)(ws + ((size_t)8  << 20));  // 32 MB partials (8 slabs)
    float*  H1 = (float*)(ws + ((size_t)40 << 20));  //  4 MB
    __bf16* Zb = (__bf16*)(ws + ((size_t)44 << 20)); //  2 MB

    // Layer 1
    proj_pack<FEAT><<<12288, 256, 0, stream>>>(H, W1_0, W1_1, W1_2, Vp);
    gemm_AV<<<dim3(128, 8), 256, 0, stream>>>(A0, A1, A2, Vp, P);
    reduce_relu<<<1024, 256, 0, stream>>>(P, b1, H1);

    // Layer 2
    proj_pack<HIDD><<<12288, 256, 0, stream>>>(H1, W2_0, W2_1, W2_2, Vp);
    gemm_AV<<<dim3(128, 8), 256, 0, stream>>>(A0, A1, A2, Vp, P);
    reduce_z<<<1024, 256, 0, stream>>>(P, b2, Zout, Zb);

    // Decoder
    zzt<<<dim3(64, 64), 256, 0, stream>>>(Zb, Ahat);
}